// Round 10
// baseline (236.368 us; speedup 1.0000x reference)
//
#include <hip/hip_runtime.h>
#include <hip/hip_bf16.h>
#include <stdint.h>

// Problem constants (from reference)
#define T_DIM   4
#define N_GRID  12288
#define C_DIM   16
#define NH      9
#define N_OUT   1024        // UP*E
#define K_DIM   144         // NH*C
#define M_TOTAL 196608      // B*V*T*N_GRID  (16 slices of 12288 rows)
#define MG_ELEMS (8 * T_DIM * N_GRID * C_DIM)   // 6291456

#define AS_STRIDE 146       // f16 elems/row (292B, odd-word stride)
#define KSTEPS    9         // 144 / 16

typedef __attribute__((ext_vector_type(4)))  float    f32x4;
typedef __attribute__((ext_vector_type(16))) float    f32x16;
typedef __attribute__((ext_vector_type(4)))  _Float16 f16x4;
typedef __attribute__((ext_vector_type(8)))  _Float16 f16x8;

// ---------------------------------------------------------------------------
// Fused pre-pass (one launch):
//  blocks 0..71    : W (144x1024 f32) -> f16 packed in MFMA B-fragment order
//  blocks 72..1095 : mg_emb f32 -> f16 (same layout), grid-stride
// Wpk layout (verified R1/R2 refcheck):
//   Wpk[((s*16+q)*64+lane)*16 + cg*8 + j] =
//     f16( W[(16*s + 8*(lane>>5) + j)*1024 + q*64 + cg*32 + (lane&31)] )
// ---------------------------------------------------------------------------
__global__ void prepass_kernel(const float* __restrict__ W,
                               _Float16* __restrict__ Wpk,
                               const float* __restrict__ mg,
                               _Float16* __restrict__ mgh) {
    if (blockIdx.x < 72) {
        const int gid  = blockIdx.x * 256 + threadIdx.x;  // 0..18431
        const int cg   = gid & 1;
        const int lane = (gid >> 1) & 63;
        const int q    = (gid >> 7) & 15;
        const int s    = gid >> 11;          // 0..8
        const int l31  = lane & 31;
        const int lhi  = lane >> 5;

        _Float16 v[8];
#pragma unroll
        for (int j = 0; j < 8; ++j) {
            const int k   = 16 * s + 8 * lhi + j;             // 0..143
            const int col = q * 64 + cg * 32 + l31;           // 0..1023
            v[j] = (_Float16)W[k * N_OUT + col];
        }
        *(f16x8*)(Wpk + (size_t)gid * 8) = *(const f16x8*)v;
    } else {
        const size_t n4 = MG_ELEMS / 4;
        const size_t nthreads = (size_t)(gridDim.x - 72) * 256;
        for (size_t i = (size_t)(blockIdx.x - 72) * 256 + threadIdx.x; i < n4; i += nthreads) {
            f32x4 f = *(const f32x4*)(mg + 4 * i);
            f16x4 h;
#pragma unroll
            for (int j = 0; j < 4; ++j) h[j] = (_Float16)f[j];
            *(f16x4*)(mgh + 4 * i) = h;
        }
    }
}

// ---------------------------------------------------------------------------
// Main kernel (R8 structure: XCD slice pinning + f16 gather + NT stores),
// with column-half split epilogue: cg=0's stores drain under cg=1's MFMAs.
// Block = 512 threads (8 waves), tile 64 rows x 512 cols, grid 6144.
// xcd = bid&7 owns slices {2*xcd, 2*xcd+1}; per-XCD L2 read set ~1.1 MB.
// ---------------------------------------------------------------------------
__global__ __launch_bounds__(512, 4) void mg_gemm_kernel(
    const _Float16* __restrict__ mgh,   // (8, 4, 12288, 16) f16
    const int*   __restrict__ vidx,     // (1, 4)
    const int*   __restrict__ adjc,     // (12288, 9)
    const _Float16* __restrict__ Wpk,   // packed B fragments
    const float* __restrict__ bias,     // (1024,)
    float* __restrict__ out)            // (196608, 1024) f32
{
    __shared__ _Float16 As[64 * AS_STRIDE];   // 18.7 KB

    // ---- XCD-pinned decode of blockIdx.x (0..6143) ----
    const int b     = blockIdx.x;
    const int xcd   = b & 7;               // round-robin XCD heuristic
    const int j     = b >> 3;              // 0..767 within XCD
    const int sl    = j / 384;             // 0..1: which of this XCD's 2 slices
    const int jj    = j - sl * 384;        // 0..383
    const int slice = xcd * 2 + sl;        // 0..15 == v*4 + t
    const int mloc  = jj >> 1;             // 0..191 row-tile within slice
    const int ytile = jj & 1;              // 0..1 col half

    const int v     = slice >> 2;
    const int t     = slice & 3;
    const int p0    = mloc * 64;           // start grid point
    const int r0    = slice * N_GRID + p0; // global output row base
    const int vi    = vidx[v];
    const _Float16* src = mgh + (size_t)(vi * T_DIM + t) * N_GRID * C_DIM;

    const int tid = threadIdx.x;

    // ---- stage A tile: 64 rows x 9 neighbors x 16 ch (f16, no cvt) ----
    for (int task = tid; task < 64 * NH; task += 512) {
        const int row = task / NH;
        const int nh  = task - row * NH;
        const int g   = adjc[p0 * NH + task];        // == adjc[(p0+row)*9 + nh]
        const _Float16* sp = src + (size_t)g * C_DIM;
        _Float16* dst = As + row * AS_STRIDE + nh * C_DIM;
        *(f16x8*)dst       = *(const f16x8*)sp;
        *(f16x8*)(dst + 8) = *(const f16x8*)(sp + 8);
    }
    __syncthreads();

    const int lane = tid & 63;
    const int w    = tid >> 6;             // wave 0..7
    const int l31  = lane & 31;
    const int lhi  = lane >> 5;
    const int q    = ytile * 8 + w;        // col-group 0..15

    const _Float16* arow0 = As + l31 * AS_STRIDE + 8 * lhi;
    const _Float16* arow1 = arow0 + 32 * AS_STRIDE;
    const _Float16* wp    = Wpk + ((size_t)q * 64 + lane) * 16;
    const int colbase     = q * 64 + l31;
    float* outp = out + (size_t)r0 * N_OUT;

    // ---- two column-half passes: B read once each; cg=0's stores drain
    //      under cg=1's MFMA phase ----
#pragma unroll
    for (int cg = 0; cg < 2; ++cg) {
        f32x16 acc0, acc1;                 // row halves for this col half
#pragma unroll
        for (int i = 0; i < 16; ++i) { acc0[i] = 0.f; acc1[i] = 0.f; }

#pragma unroll
        for (int s = 0; s < KSTEPS; ++s) {
            f16x8 a0 = *(const f16x8*)(arow0 + s * C_DIM);
            f16x8 a1 = *(const f16x8*)(arow1 + s * C_DIM);
            f16x8 bb = *(const f16x8*)(wp + (size_t)s * (16 * 64 * 16) + cg * 8);
            acc0 = __builtin_amdgcn_mfma_f32_32x32x16_f16(a0, bb, acc0, 0, 0, 0);
            acc1 = __builtin_amdgcn_mfma_f32_32x32x16_f16(a1, bb, acc1, 0, 0, 0);
        }

        const int cb = colbase + 32 * cg;
        const float bf = bias[cb];
#pragma unroll
        for (int r = 0; r < 16; ++r) {
            const int rr = (r & 3) + 8 * (r >> 2) + 4 * lhi;   // 0..31
            __builtin_nontemporal_store(acc0[r] + bf, &outp[(size_t)rr * N_OUT + cb]);
            __builtin_nontemporal_store(acc1[r] + bf, &outp[(size_t)(rr + 32) * N_OUT + cb]);
        }
    }
}

// ---------------------------------------------------------------------------
extern "C" void kernel_launch(void* const* d_in, const int* in_sizes, int n_in,
                              void* d_out, int out_size, void* d_ws, size_t ws_size,
                              hipStream_t stream) {
    const float* mg   = (const float*)d_in[0];   // mg_emb
    const int*   vidx = (const int*)  d_in[1];   // var_indices
    const int*   adjc = (const int*)  d_in[2];   // adjc
    const float* W    = (const float*)d_in[3];   // W
    const float* bias = (const float*)d_in[4];   // b
    float*       out  = (float*)d_out;

    _Float16* Wpk = (_Float16*)d_ws;                         // 294912 B
    _Float16* mgh = (_Float16*)((char*)d_ws + (1 << 20));    // 12.6 MB

    // fused pre-pass: W pack + mg f32->f16
    prepass_kernel<<<dim3(72 + 1024), dim3(256), 0, stream>>>(W, Wpk, mg, mgh);

    // gather+GEMM: 64x512 tiles, XCD-pinned slices, NT stores
    mg_gemm_kernel<<<dim3(M_TOTAL / 64 * 2), dim3(512), 0, stream>>>(
        mgh, vidx, adjc, Wpk, bias, out);
}

// Round 11
// 146.154 us; speedup vs baseline: 1.6173x; 1.6173x over previous
//
#include <hip/hip_runtime.h>
#include <hip/hip_bf16.h>
#include <stdint.h>

// Problem constants (from reference)
#define T_DIM   4
#define N_GRID  12288
#define C_DIM   16
#define NH      9
#define N_OUT   1024        // UP*E
#define K_DIM   144         // NH*C
#define M_TOTAL 196608      // B*V*T*N_GRID  (16 slices of 12288 rows)

#define AS_STRIDE 146       // f16 elems/row (292B, odd-word stride)
#define KSTEPS    9         // 144 / 16

typedef __attribute__((ext_vector_type(4)))  float    f32x4;
typedef __attribute__((ext_vector_type(16))) float    f32x16;
typedef __attribute__((ext_vector_type(4)))  _Float16 f16x4;
typedef __attribute__((ext_vector_type(8)))  _Float16 f16x8;

// ---------------------------------------------------------------------------
// Pre-pass: W (144x1024 f32) -> f16 packed in MFMA B-fragment order for
// v_mfma_f32_32x32x16_f16 (layout verified by R1/R2 refcheck):
//   Wpk[((s*16+q)*64+lane)*16 + cg*8 + j] =
//     f16( W[(16*s + 8*(lane>>5) + j)*1024 + q*64 + cg*32 + (lane&31)] )
// ---------------------------------------------------------------------------
__global__ void pack_w_kernel(const float* __restrict__ W,
                              _Float16* __restrict__ Wpk) {
    const int gid  = blockIdx.x * blockDim.x + threadIdx.x;  // 0..18431
    const int cg   = gid & 1;
    const int lane = (gid >> 1) & 63;
    const int q    = (gid >> 7) & 15;
    const int s    = gid >> 11;          // 0..8
    const int l31  = lane & 31;
    const int lhi  = lane >> 5;

    _Float16 v[8];
#pragma unroll
    for (int j = 0; j < 8; ++j) {
        const int k   = 16 * s + 8 * lhi + j;             // 0..143
        const int col = q * 64 + cg * 32 + l31;           // 0..1023
        v[j] = (_Float16)W[k * N_OUT + col];
    }
    *(f16x8*)(Wpk + (size_t)gid * 8) = *(const f16x8*)v;
}

// ---------------------------------------------------------------------------
// Main kernel — exact R8 structure (XCD slice pinning, single MFMA phase,
// NT scattered epilogue); ONLY change vs R8: gather reads f32 mg directly
// with inline f16 cvt (no conv_mg pre-pass).
// Block = 512 threads (8 waves), tile 64 rows x 512 cols, grid 6144.
// xcd = bid&7 owns slices {2*xcd, 2*xcd+1}; per-XCD L2 read set ~2.3 MB
// (2 f32 slices 1.57MB + Wpk 288KB + adjc 432KB) stays L2-resident.
// ---------------------------------------------------------------------------
__global__ __launch_bounds__(512, 4) void mg_gemm_kernel(
    const float* __restrict__ mg,       // (8, 4, 12288, 16) f32
    const int*   __restrict__ vidx,     // (1, 4)
    const int*   __restrict__ adjc,     // (12288, 9)
    const _Float16* __restrict__ Wpk,   // packed B fragments
    const float* __restrict__ bias,     // (1024,)
    float* __restrict__ out)            // (196608, 1024) f32
{
    __shared__ _Float16 As[64 * AS_STRIDE];   // 18.7 KB

    // ---- XCD-pinned decode of blockIdx.x (0..6143) ----
    const int b     = blockIdx.x;
    const int xcd   = b & 7;               // round-robin XCD heuristic
    const int j     = b >> 3;              // 0..767 within XCD
    const int sl    = j / 384;             // 0..1: which of this XCD's 2 slices
    const int jj    = j - sl * 384;        // 0..383
    const int slice = xcd * 2 + sl;        // 0..15 == v*4 + t
    const int mloc  = jj >> 1;             // 0..191 row-tile within slice
    const int ytile = jj & 1;              // 0..1 col half

    const int v     = slice >> 2;
    const int t     = slice & 3;
    const int p0    = mloc * 64;           // start grid point
    const int r0    = slice * N_GRID + p0; // global output row base
    const int vi    = vidx[v];
    const float* src = mg + (size_t)(vi * T_DIM + t) * N_GRID * C_DIM;

    const int tid = threadIdx.x;

    // ---- stage A tile: 64 rows x 9 neighbors x 16 ch, f32 -> f16 inline ----
    for (int task = tid; task < 64 * NH; task += 512) {
        const int row = task / NH;
        const int nh  = task - row * NH;
        const int g   = adjc[p0 * NH + task];        // == adjc[(p0+row)*9 + nh]
        const float* sp = src + (size_t)g * C_DIM;
        f32x4 f0 = *(const f32x4*)(sp + 0);
        f32x4 f1 = *(const f32x4*)(sp + 4);
        f32x4 f2 = *(const f32x4*)(sp + 8);
        f32x4 f3 = *(const f32x4*)(sp + 12);
        f16x8 h0, h1;
#pragma unroll
        for (int i = 0; i < 4; ++i) {
            h0[i]     = (_Float16)f0[i];
            h0[i + 4] = (_Float16)f1[i];
            h1[i]     = (_Float16)f2[i];
            h1[i + 4] = (_Float16)f3[i];
        }
        _Float16* dst = As + row * AS_STRIDE + nh * C_DIM;
        *(f16x8*)dst       = h0;
        *(f16x8*)(dst + 8) = h1;
    }
    __syncthreads();

    const int lane = tid & 63;
    const int w    = tid >> 6;             // wave 0..7
    const int l31  = lane & 31;
    const int lhi  = lane >> 5;
    const int q    = ytile * 8 + w;        // col-group 0..15

    f32x16 acc00, acc01, acc10, acc11;     // [colhalf][rowhalf]
#pragma unroll
    for (int i = 0; i < 16; ++i) { acc00[i]=0.f; acc01[i]=0.f; acc10[i]=0.f; acc11[i]=0.f; }

    const _Float16* arow0 = As + l31 * AS_STRIDE + 8 * lhi;
    const _Float16* arow1 = arow0 + 32 * AS_STRIDE;
    const _Float16* wp    = Wpk + ((size_t)q * 64 + lane) * 16;

#pragma unroll
    for (int s = 0; s < KSTEPS; ++s) {
        f16x8 a0 = *(const f16x8*)(arow0 + s * C_DIM);
        f16x8 a1 = *(const f16x8*)(arow1 + s * C_DIM);
        const _Float16* bp = wp + (size_t)s * (16 * 64 * 16);
        f16x8 b0 = *(const f16x8*)(bp + 0);
        f16x8 b1 = *(const f16x8*)(bp + 8);
        acc00 = __builtin_amdgcn_mfma_f32_32x32x16_f16(a0, b0, acc00, 0, 0, 0);
        acc01 = __builtin_amdgcn_mfma_f32_32x32x16_f16(a1, b0, acc01, 0, 0, 0);
        acc10 = __builtin_amdgcn_mfma_f32_32x32x16_f16(a0, b1, acc10, 0, 0, 0);
        acc11 = __builtin_amdgcn_mfma_f32_32x32x16_f16(a1, b1, acc11, 0, 0, 0);
    }

    // ---- epilogue: add bias, NT scattered stores (single phase, as R8) ----
    const int colbase = q * 64 + l31;
    const float b0f = bias[colbase];
    const float b1f = bias[colbase + 32];
    float* outp = out + (size_t)r0 * N_OUT;

#pragma unroll
    for (int r = 0; r < 16; ++r) {
        const int rr = (r & 3) + 8 * (r >> 2) + 4 * lhi;   // 0..31
        __builtin_nontemporal_store(acc00[r] + b0f, &outp[(size_t)rr * N_OUT + colbase]);
        __builtin_nontemporal_store(acc10[r] + b1f, &outp[(size_t)rr * N_OUT + colbase + 32]);
        __builtin_nontemporal_store(acc01[r] + b0f, &outp[(size_t)(rr + 32) * N_OUT + colbase]);
        __builtin_nontemporal_store(acc11[r] + b1f, &outp[(size_t)(rr + 32) * N_OUT + colbase + 32]);
    }
}

// ---------------------------------------------------------------------------
extern "C" void kernel_launch(void* const* d_in, const int* in_sizes, int n_in,
                              void* d_out, int out_size, void* d_ws, size_t ws_size,
                              hipStream_t stream) {
    const float* mg   = (const float*)d_in[0];   // mg_emb
    const int*   vidx = (const int*)  d_in[1];   // var_indices
    const int*   adjc = (const int*)  d_in[2];   // adjc
    const float* W    = (const float*)d_in[3];   // W
    const float* bias = (const float*)d_in[4];   // b
    float*       out  = (float*)d_out;

    _Float16* Wpk = (_Float16*)d_ws;             // 294912 B

    pack_w_kernel<<<dim3(72), dim3(256), 0, stream>>>(W, Wpk);

    // gather+GEMM: 64x512 tiles, XCD-pinned slices, NT stores (R8 + f32 gather)
    mg_gemm_kernel<<<dim3(M_TOTAL / 64 * 2), dim3(512), 0, stream>>>(
        mg, vidx, adjc, Wpk, bias, out);
}